// Round 14
// baseline (432.746 us; speedup 1.0000x reference)
//
#include <hip/hip_runtime.h>
#include <hip/hip_fp16.h>

// GATv2 x3 + MLP head on MI355X.
// R17: (1) xmm_body W-halving: stage WT_l -> MFMA L -> restage WT_r -> MFMA R
// (A-frags live in regs). LDS xmm1 48->32KB (k_front bin blocks 3->4/CU),
// xmm2 64->48KB. (2) xmm3 fused into k_gat<2> epilogue: h row (fp16, LDS)
// dotted against swizzled t3 via fdot2, one output/lane; A3/B3 land in Cb;
// xmm3 launch + round-trip gone. (3) bcnt zeroing folded into k_wprep.
// 9 -> 7 launches. gat loop stays R13 known-good even-rounded form.

constexpr int N = 100000;
constexpr int E = 1600000;
constexpr int S = 48;       // slots per node (cap; stores guarded)

constexpr int NBUK = (N + 127) >> 7;          // 782 buckets of 128 nodes
constexpr int BCAP = 384;                     // per (bucket, class) cap; mean 256
constexpr int EPB = 8192;                     // edges per bin block
constexpr int BIN_B = (E + EPB - 1) / EPB;    // 196 bin blocks
constexpr int XMM_B = (N + 127) / 128;        // xmm blocks (128 nodes each)

typedef _Float16 half8_t __attribute__((ext_vector_type(8)));
typedef _Float16 half4_t __attribute__((ext_vector_type(4)));
typedef _Float16 h2 __attribute__((ext_vector_type(2)));
typedef float f32x4 __attribute__((ext_vector_type(4)));

// ---------------- bin body: block-local counting sort into (bucket,class) ---

template <int NT>
__device__ __forceinline__ void bin_body(const int* __restrict__ ei,
                                         int* __restrict__ bcnt,
                                         unsigned* __restrict__ bbuf,
                                         int blk, int cls) {
  __shared__ int hist[NBUK];
  const int tid = threadIdx.x;
  const int e0 = blk * EPB;
  for (int i = tid; i < NBUK; i += NT) hist[i] = 0;
  __syncthreads();
  // phase 1: LDS histogram of dst buckets (block-private)
  #pragma unroll 4
  for (int j = 0; j < EPB / NT; ++j) {
    const int e = e0 + j * NT + tid;
    if (e < E) atomicAdd(&hist[ei[E + e] >> 7], 1);
  }
  __syncthreads();
  // phase 2: reserve a contiguous range per bucket (one global atomic each)
  for (int i = tid; i < NBUK; i += NT) {
    const int h = hist[i];
    hist[i] = h ? atomicAdd(&bcnt[i * 8 + cls], h) : 0;
  }
  __syncthreads();
  // phase 3: scatter at base+rank (edge window is L2-hot from phase 1)
  #pragma unroll 4
  for (int j = 0; j < EPB / NT; ++j) {
    const int e = e0 + j * NT + tid;
    if (e < E) {
      const int src = ei[e];
      const int dst = ei[E + e];
      const int b = dst >> 7;
      const int pos = atomicAdd(&hist[b], 1);   // LDS: base + local rank
      if (pos < BCAP)
        bbuf[(size_t)(b * 8 + cls) * BCAP + pos] =
            ((unsigned)(dst & 127) << 17) | (unsigned)src;
    }
  }
}

// ---------------- pass 2: per-bucket insert with LDS slot claims ------------
// Slot 0 of every node is the (deterministic) self-loop.

__global__ __launch_bounds__(256) void k_insert(const int* __restrict__ bcnt,
                                                const unsigned* __restrict__ bbuf,
                                                int* __restrict__ deg,
                                                int* __restrict__ ebuf) {
  __shared__ int cnt[128];
  const int b = blockIdx.x;
  const int tid = threadIdx.x;
  const int node0 = b * 128 + tid;
  if (tid < 128) {
    cnt[tid] = 1;                                   // self-loop occupies slot 0
    if (node0 < N) ebuf[node0 * S] = node0;
  }
  __syncthreads();
  #pragma unroll 1
  for (int c = 0; c < 8; ++c) {
    const int n = min(bcnt[b * 8 + c], BCAP);
    const unsigned* arr = bbuf + (size_t)(b * 8 + c) * BCAP;
    for (int i = tid; i < n; i += 256) {
      const unsigned ent = arr[i];
      const int dlo = (int)(ent >> 17);
      const int src = (int)(ent & 0x1FFFFu);
      const int pos = atomicAdd(&cnt[dlo], 1);   // LDS atomic, block-exclusive
      if (pos < S) ebuf[(b * 128 + dlo) * S + pos] = src;
    }
  }
  __syncthreads();
  if (tid < 128 && node0 < N) deg[node0] = cnt[tid];
}

// ---------------- weight prep: fp32 [K][M] -> fp16 transposed+swizzled ------
// WT[m][k] stored at m*K + (k ^ ((m&7)<<3)). Also zeroes bcnt (fused memset).

template <int K, int M>
__device__ __forceinline__ void wprep_body(const float* __restrict__ src,
                                           __half* __restrict__ dst, int blk) {
  const int idx = blk * 256 + threadIdx.x;     // grid sized so idx < K*M
  const int k = idx / M;
  const int m = idx % M;
  ((_Float16*)dst)[m * K + (k ^ ((m & 7) << 3))] = (_Float16)src[idx];
}

__global__ __launch_bounds__(256) void k_wprep(
    const float* w1l, const float* w1r, const float* w2l, const float* w2r,
    const float* w3l, const float* w3r,
    __half* o1l, __half* o1r, __half* o2l, __half* o2r,
    __half* o3l, __half* o3r, int* bcnt) {
  const int gi = blockIdx.x * 256 + threadIdx.x;
  if (gi < NBUK * 8) bcnt[gi] = 0;
  int b = blockIdx.x;                 // sizes: 4x32 blocks (8192) + 2x8 (2048)
  if      (b < 32)  wprep_body<64, 128>(w1l, o1l, b);
  else if (b < 64)  wprep_body<64, 128>(w1r, o1r, b - 32);
  else if (b < 96)  wprep_body<128, 64>(w2l, o2l, b - 64);
  else if (b < 128) wprep_body<128, 64>(w2r, o2r, b - 96);
  else if (b < 136) wprep_body<64, 32>(w3l, o3l, b - 128);
  else              wprep_body<64, 32>(w3r, o3r, b - 136);
}

// ---------------- MFMA transform body: y = x @ w + b, L and R fused ---------
// Block: 128 nodes, 8 waves, 512 threads; wave = 16 rows x M cols.
// W-halved LDS: stage WT_l -> MFMA L -> restage WT_r -> MFMA R.

template <int K, int M, bool FP16IN>
__device__ __forceinline__ void xmm_body(const void* __restrict__ xin,
                                         const __half* __restrict__ wtl,
                                         const __half* __restrict__ wtr,
                                         const float* __restrict__ bl,
                                         const float* __restrict__ br,
                                         __half* __restrict__ Aout,
                                         __half* __restrict__ Bout, int blk) {
  constexpr int NPB = 128;           // nodes per block
  constexpr int XSZ = NPB * K;       // halfs
  constexpr int WSZ = M * K;         // halfs per weight matrix
  constexpr int KS = K / 32;         // MFMA k-steps
  constexpr int CT = M / 16;         // col tiles
  constexpr int PSZ = (XSZ + WSZ) > (NPB * M) ? (XSZ + WSZ) : (NPB * M);
  __shared__ _Float16 pool[PSZ];

  const int tid = threadIdx.x;
  const int node0 = blk * NPB;

  // --- stage X tile (swizzled) ---
  if constexpr (!FP16IN) {
    const float* x = (const float*)xin;
    for (int i = tid; i < NPB * (K / 4); i += 512) {
      const int row = i / (K / 4);
      const int c4 = i % (K / 4);
      const int grow = min(node0 + row, N - 1);
      float4 v = reinterpret_cast<const float4*>(x)[(size_t)grow * (K / 4) + c4];
      const int k0 = c4 * 4;
      const int hidx = row * K + (k0 ^ ((row & 7) << 3));
      *reinterpret_cast<half4_t*>(&pool[hidx]) =
          (half4_t){(_Float16)v.x, (_Float16)v.y, (_Float16)v.z, (_Float16)v.w};
    }
  } else {
    const uint4* x = (const uint4*)xin;   // rows of K halfs
    for (int i = tid; i < NPB * (K / 8); i += 512) {
      const int row = i / (K / 8);
      const int c8 = i % (K / 8);
      const int grow = min(node0 + row, N - 1);
      uint4 v = x[(size_t)grow * (K / 8) + c8];
      const int k0 = c8 * 8;
      *reinterpret_cast<uint4*>(&pool[row * K + (k0 ^ ((row & 7) << 3))]) = v;
    }
  }
  // --- stage WT_l ---
  for (int i = tid; i < WSZ / 8; i += 512)
    reinterpret_cast<uint4*>(&pool[XSZ])[i] =
        reinterpret_cast<const uint4*>(wtl)[i];
  __syncthreads();

  const int lane = tid & 63;
  const int wid = tid >> 6;          // 0..7
  const int r0 = wid * 16;

  // --- A fragments (persist across both W phases) ---
  half8_t af[KS];
  #pragma unroll
  for (int ks = 0; ks < KS; ++ks) {
    const int row = r0 + (lane & 15);
    const int k0 = ks * 32 + (lane >> 4) * 8;
    af[ks] = *reinterpret_cast<const half8_t*>(
        &pool[row * K + (k0 ^ ((row & 7) << 3))]);
  }

  f32x4 accl[CT], accr[CT];
  #pragma unroll
  for (int ct = 0; ct < CT; ++ct) {
    accl[ct] = (f32x4){0.f, 0.f, 0.f, 0.f};
    accr[ct] = (f32x4){0.f, 0.f, 0.f, 0.f};
  }

  #pragma unroll
  for (int ct = 0; ct < CT; ++ct) {
    #pragma unroll
    for (int ks = 0; ks < KS; ++ks) {
      const int col = ct * 16 + (lane & 15);
      const int k0 = ks * 32 + (lane >> 4) * 8;
      half8_t bf = *reinterpret_cast<const half8_t*>(
          &pool[XSZ + col * K + (k0 ^ ((col & 7) << 3))]);
      accl[ct] = __builtin_amdgcn_mfma_f32_16x16x32_f16(af[ks], bf, accl[ct], 0, 0, 0);
    }
  }
  __syncthreads();
  // --- restage WT_r into the same region ---
  for (int i = tid; i < WSZ / 8; i += 512)
    reinterpret_cast<uint4*>(&pool[XSZ])[i] =
        reinterpret_cast<const uint4*>(wtr)[i];
  __syncthreads();
  #pragma unroll
  for (int ct = 0; ct < CT; ++ct) {
    #pragma unroll
    for (int ks = 0; ks < KS; ++ks) {
      const int col = ct * 16 + (lane & 15);
      const int k0 = ks * 32 + (lane >> 4) * 8;
      half8_t bf = *reinterpret_cast<const half8_t*>(
          &pool[XSZ + col * K + (k0 ^ ((col & 7) << 3))]);
      accr[ct] = __builtin_amdgcn_mfma_f32_16x16x32_f16(af[ks], bf, accr[ct], 0, 0, 0);
    }
  }

  // --- epilogue: D -> LDS (unswizzled) -> coalesced global stores ---
  __syncthreads();   // staging regions dead; D region aliases pool[0..NPB*M)
  #pragma unroll
  for (int ct = 0; ct < CT; ++ct) {
    const int col = ct * 16 + (lane & 15);
    const float bb = bl[col];
    #pragma unroll
    for (int r = 0; r < 4; ++r) {
      const int row = r0 + (lane >> 4) * 4 + r;
      pool[row * M + col] = (_Float16)(accl[ct][r] + bb);
    }
  }
  __syncthreads();
  for (int i = tid; i < NPB * (M / 8); i += 512) {
    const int row = i / (M / 8);
    const int j = i % (M / 8);
    const int g = node0 + row;
    if (g < N)
      reinterpret_cast<uint4*>(Aout + (size_t)g * M)[j] =
          reinterpret_cast<uint4*>(&pool[row * M])[j];
  }
  __syncthreads();
  #pragma unroll
  for (int ct = 0; ct < CT; ++ct) {
    const int col = ct * 16 + (lane & 15);
    const float bb = br[col];
    #pragma unroll
    for (int r = 0; r < 4; ++r) {
      const int row = r0 + (lane >> 4) * 4 + r;
      pool[row * M + col] = (_Float16)(accr[ct][r] + bb);
    }
  }
  __syncthreads();
  for (int i = tid; i < NPB * (M / 8); i += 512) {
    const int row = i / (M / 8);
    const int j = i % (M / 8);
    const int g = node0 + row;
    if (g < N)
      reinterpret_cast<uint4*>(Bout + (size_t)g * M)[j] =
          reinterpret_cast<uint4*>(&pool[row * M])[j];
  }
}

// ---------------- fused front: layer-1 xmm blocks + bin blocks -------------

__global__ __launch_bounds__(512) void k_front(const float* __restrict__ x,
                                               const __half* __restrict__ t1l,
                                               const __half* __restrict__ t1r,
                                               const float* __restrict__ b1l,
                                               const float* __restrict__ b1r,
                                               __half* __restrict__ A,
                                               __half* __restrict__ B,
                                               const int* __restrict__ ei,
                                               int* __restrict__ bcnt,
                                               unsigned* __restrict__ bbuf) {
  const int blk = blockIdx.x;
  if (blk < XMM_B) {
    xmm_body<64, 128, false>(x, t1l, t1r, b1l, b1r, A, B, blk);
    return;
  }
  bin_body<512>(ei, bcnt, bbuf, blk - XMM_B, blk & 7);
}

// ---------------- standalone xmm (layer 2) ----------------

template <int K, int M, bool FP16IN>
__global__ __launch_bounds__(512) void k_xmm(const void* __restrict__ xin,
                                             const __half* __restrict__ wtl,
                                             const __half* __restrict__ wtr,
                                             const float* __restrict__ bl,
                                             const float* __restrict__ br,
                                             __half* __restrict__ Aout,
                                             __half* __restrict__ Bout) {
  xmm_body<K, M, FP16IN>(xin, wtl, wtr, bl, br, Aout, Bout, blockIdx.x);
}

// ---------------- GATv2 aggregation: one wave per dst node ----------------
// Lane holds 8 fp16 features; one wave load covers a full row. Packed fp16
// score path + v_dot2_f32_f16; fp32 acc via v_fma_mix. 2-phase A/B pipeline
// (R13 known-good). MODE: 0=plain fp16 out, 1=fused layer-3 transform
// (h -> A3,B3 via fdot2 vs swizzled t3), 2=fused MLP head.

template <int CTRL>
__device__ __forceinline__ float dpp_add(float x) {
  return x + __builtin_bit_cast(float,
      __builtin_amdgcn_update_dpp(0, __builtin_bit_cast(int, x),
                                  CTRL, 0xF, 0xF, true));
}

template <int H, int MODE>
__global__ __launch_bounds__(256) void k_gat(const __half* __restrict__ xl,
                                             const __half* __restrict__ xr,
                                             const float* __restrict__ att,
                                             const float* __restrict__ bias,
                                             const int* __restrict__ deg,
                                             const int* __restrict__ ebuf,
                                             void* __restrict__ out0,
                                             void* __restrict__ out1,
                                             const __half* __restrict__ hw0,
                                             const __half* __restrict__ hw1,
                                             const float* __restrict__ p0,
                                             const float* __restrict__ p1,
                                             const float* __restrict__ p2,
                                             const float* __restrict__ p3) {
  constexpr int F = H * 32;
  constexpr int F8 = F / 8;        // 16B chunks (8 halfs) per row
  constexpr int LPE = F8;          // lanes per edge: 16 / 8 / 4
  constexpr int EPI = 64 / LPE;    // edges per iteration: 4 / 8 / 16
  constexpr float LOG2E = 1.44269504088896f;
  const int lane = threadIdx.x & 63;
  const int node = (blockIdx.x * blockDim.x + threadIdx.x) >> 6;
  if (node >= N) return;    // never taken (N % 4 == 0, exact grid)
  const int li = lane & (LPE - 1);  // 16B chunk index within row
  const int eg = lane / LPE;

  const uint4* xl4 = reinterpret_cast<const uint4*>(xl);
  const uint4* xr4 = reinterpret_cast<const uint4*>(xr);

  // xi: 8 fp16 channels kept packed
  const uint4 xiraw = xr4[(unsigned)node * F8 + li];
  h2 xi2[4];
  xi2[0] = __builtin_bit_cast(h2, xiraw.x);
  xi2[1] = __builtin_bit_cast(h2, xiraw.y);
  xi2[2] = __builtin_bit_cast(h2, xiraw.z);
  xi2[3] = __builtin_bit_cast(h2, xiraw.w);

  // att: fp32 -> pre-scaled fp16 pairs
  const float4 at0 = reinterpret_cast<const float4*>(att)[li * 2];
  const float4 at1 = reinterpret_cast<const float4*>(att)[li * 2 + 1];
  h2 at2[4];
  at2[0] = (h2){(_Float16)(at0.x * LOG2E), (_Float16)(at0.y * LOG2E)};
  at2[1] = (h2){(_Float16)(at0.z * LOG2E), (_Float16)(at0.w * LOG2E)};
  at2[2] = (h2){(_Float16)(at1.x * LOG2E), (_Float16)(at1.y * LOG2E)};
  at2[3] = (h2){(_Float16)(at1.z * LOG2E), (_Float16)(at1.w * LOG2E)};
  const h2 c02 = {(_Float16)0.2f, (_Float16)0.2f};

  float4 acc0 = make_float4(0.f, 0.f, 0.f, 0.f);
  float4 acc1 = make_float4(0.f, 0.f, 0.f, 0.f);
  float l = 0.f;

  const int* row = ebuf + node * S;
  const int dn = min(deg[node], S);   // deg >= 1 (self loop)
  const int last = dn - 1;
  const int iters = (dn + EPI - 1) / EPI;

  auto process = [&](const uint4& raw, bool valid) {
    h2 xj0 = __builtin_bit_cast(h2, raw.x);
    h2 xj1 = __builtin_bit_cast(h2, raw.y);
    h2 xj2 = __builtin_bit_cast(h2, raw.z);
    h2 xj3 = __builtin_bit_cast(h2, raw.w);
    float t = 0.f;
    h2 v;
    v = xi2[0] + xj0; v = __builtin_elementwise_max(v, v * c02);
    t = __builtin_amdgcn_fdot2(at2[0], v, t, false);
    v = xi2[1] + xj1; v = __builtin_elementwise_max(v, v * c02);
    t = __builtin_amdgcn_fdot2(at2[1], v, t, false);
    v = xi2[2] + xj2; v = __builtin_elementwise_max(v, v * c02);
    t = __builtin_amdgcn_fdot2(at2[2], v, t, false);
    v = xi2[3] + xj3; v = __builtin_elementwise_max(v, v * c02);
    t = __builtin_amdgcn_fdot2(at2[3], v, t, false);
    // head = one 4-lane quad: butterfly via quad_perm DPP (VALU, no LDS pipe)
    t = dpp_add<0xB1>(t);   // xor 1: [1,0,3,2]
    t = dpp_add<0x4E>(t);   // xor 2: [2,3,0,1]
    float pm = valid ? exp2f(t) : 0.f;
    l += pm;
    // fp32 acc; (float)h * f + acc folds to v_fma_mix_f32
    acc0.x = fmaf(pm, (float)xj0[0], acc0.x);
    acc0.y = fmaf(pm, (float)xj0[1], acc0.y);
    acc0.z = fmaf(pm, (float)xj1[0], acc0.z);
    acc0.w = fmaf(pm, (float)xj1[1], acc0.w);
    acc1.x = fmaf(pm, (float)xj2[0], acc1.x);
    acc1.y = fmaf(pm, (float)xj2[1], acc1.y);
    acc1.z = fmaf(pm, (float)xj3[0], acc1.z);
    acc1.w = fmaf(pm, (float)xj3[1], acc1.w);
  };

  // pipeline warm-up: src prefetched 2 iterations ahead, gather 1 ahead
  int i = eg;
  bool vA = i < dn;
  int s0 = row[min(i, last)];
  i += EPI;
  uint4 xjA = xl4[(unsigned)s0 * F8 + li];
  bool vB = i < dn;
  int sN = row[min(i, last)];
  i += EPI;
  uint4 xjB;

  for (int it = 0; it < iters; it += 2) {
    // ---- phase A ----
    xjB = xl4[(unsigned)sN * F8 + li];             // gather it+1
    bool vn = i < dn;
    sN = row[min(i, last)];                        // src it+2
    i += EPI;
    process(xjA, vA);
    vA = vn;
    // ---- phase B ----
    xjA = xl4[(unsigned)sN * F8 + li];             // gather it+2
    vn = i < dn;
    sN = row[min(i, last)];                        // src it+3
    i += EPI;
    process(xjB, vB);
    vB = vn;
  }

  // combine the EPI edge slots (once per node)
  #pragma unroll
  for (int ofs = LPE; ofs < 64; ofs <<= 1) {
    acc0.x += __shfl_xor(acc0.x, ofs);
    acc0.y += __shfl_xor(acc0.y, ofs);
    acc0.z += __shfl_xor(acc0.z, ofs);
    acc0.w += __shfl_xor(acc0.w, ofs);
    acc1.x += __shfl_xor(acc1.x, ofs);
    acc1.y += __shfl_xor(acc1.y, ofs);
    acc1.z += __shfl_xor(acc1.z, ofs);
    acc1.w += __shfl_xor(acc1.w, ofs);
    l      += __shfl_xor(l, ofs);
  }

  if constexpr (MODE == 0) {
    __half* out = (__half*)out0;
    if (lane < LPE) {
      const float inv = 1.f / (l + 1e-16f);
      const float4 bv0 = reinterpret_cast<const float4*>(bias)[li * 2];
      const float4 bv1 = reinterpret_cast<const float4*>(bias)[li * 2 + 1];
      float r[8];
      r[0] = fmaxf(acc0.x * inv + bv0.x, 0.f);
      r[1] = fmaxf(acc0.y * inv + bv0.y, 0.f);
      r[2] = fmaxf(acc0.z * inv + bv0.z, 0.f);
      r[3] = fmaxf(acc0.w * inv + bv0.w, 0.f);
      r[4] = fmaxf(acc1.x * inv + bv1.x, 0.f);
      r[5] = fmaxf(acc1.y * inv + bv1.y, 0.f);
      r[6] = fmaxf(acc1.z * inv + bv1.z, 0.f);
      r[7] = fmaxf(acc1.w * inv + bv1.w, 0.f);
      uint4 o;
      #pragma unroll
      for (int p = 0; p < 4; ++p) {
        const h2 hh = {(_Float16)r[2 * p], (_Float16)r[2 * p + 1]};
        (&o.x)[p] = __builtin_bit_cast(unsigned, hh);
      }
      reinterpret_cast<uint4*>(out)[(unsigned)node * F8 + li] = o;
    }
  } else if constexpr (MODE == 1) {
    // ---- fused layer-3 L/R transform: h (64ch) -> A3,B3 (32ch each) ----
    __shared__ _Float16 hsh[4][64];
    const int n = threadIdx.x >> 6;
    if (lane < LPE) {
      const float inv = 1.f / (l + 1e-16f);
      const float4 bv0 = reinterpret_cast<const float4*>(bias)[li * 2];
      const float4 bv1 = reinterpret_cast<const float4*>(bias)[li * 2 + 1];
      float r[8];
      r[0] = fmaxf(acc0.x * inv + bv0.x, 0.f);
      r[1] = fmaxf(acc0.y * inv + bv0.y, 0.f);
      r[2] = fmaxf(acc0.z * inv + bv0.z, 0.f);
      r[3] = fmaxf(acc0.w * inv + bv0.w, 0.f);
      r[4] = fmaxf(acc1.x * inv + bv1.x, 0.f);
      r[5] = fmaxf(acc1.y * inv + bv1.y, 0.f);
      r[6] = fmaxf(acc1.z * inv + bv1.z, 0.f);
      r[7] = fmaxf(acc1.w * inv + bv1.w, 0.f);
      uint4 o;
      #pragma unroll
      for (int p = 0; p < 4; ++p) {
        const h2 hh = {(_Float16)r[2 * p], (_Float16)r[2 * p + 1]};
        (&o.x)[p] = __builtin_bit_cast(unsigned, hh);
      }
      *reinterpret_cast<uint4*>(&hsh[n][li * 8]) = o;
    }
    __syncthreads();
    {
      const int m = lane & 31;
      const bool rs = lane >= 32;
      const __half* wt = rs ? hw1 : hw0;       // t3 [32][64] swizzled
      const float* bb = rs ? p1 : p0;
      const uint4* w4 = reinterpret_cast<const uint4*>(wt) + m * 8;
      const int sw = m & 7;
      float acc = 0.f;
      #pragma unroll
      for (int jj = 0; jj < 8; ++jj) {
        const uint4 w = w4[jj];
        const uint4 hv = *reinterpret_cast<const uint4*>(&hsh[n][(jj ^ sw) << 3]);
        acc = __builtin_amdgcn_fdot2(__builtin_bit_cast(h2, w.x),
                                     __builtin_bit_cast(h2, hv.x), acc, false);
        acc = __builtin_amdgcn_fdot2(__builtin_bit_cast(h2, w.y),
                                     __builtin_bit_cast(h2, hv.y), acc, false);
        acc = __builtin_amdgcn_fdot2(__builtin_bit_cast(h2, w.z),
                                     __builtin_bit_cast(h2, hv.z), acc, false);
        acc = __builtin_amdgcn_fdot2(__builtin_bit_cast(h2, w.w),
                                     __builtin_bit_cast(h2, hv.w), acc, false);
      }
      acc += bb[m];
      __half* dst = rs ? (__half*)out1 : (__half*)out0;
      dst[(unsigned)node * 32 + m] = (__half)(_Float16)acc;
    }
  } else {
    // ---- fused MLP head: h row -> LDS -> 32->16->2 + sigmoid/tanh ----
    __shared__ float hsh[4][32];
    if (lane < LPE) {
      const float inv = 1.f / (l + 1e-16f);
      const float4 bv0 = reinterpret_cast<const float4*>(bias)[li * 2];
      const float4 bv1 = reinterpret_cast<const float4*>(bias)[li * 2 + 1];
      float* hr = &hsh[threadIdx.x >> 6][li * 8];
      hr[0] = fmaxf(acc0.x * inv + bv0.x, 0.f);
      hr[1] = fmaxf(acc0.y * inv + bv0.y, 0.f);
      hr[2] = fmaxf(acc0.z * inv + bv0.z, 0.f);
      hr[3] = fmaxf(acc0.w * inv + bv0.w, 0.f);
      hr[4] = fmaxf(acc1.x * inv + bv1.x, 0.f);
      hr[5] = fmaxf(acc1.y * inv + bv1.y, 0.f);
      hr[6] = fmaxf(acc1.z * inv + bv1.z, 0.f);
      hr[7] = fmaxf(acc1.w * inv + bv1.w, 0.f);
    }
    __syncthreads();
    const int n = threadIdx.x >> 6;   // node slot within block
    const int j = lane & 15;          // hidden unit
    const int q = lane >> 4;          // k-octet
    float a = 0.f;
    #pragma unroll
    for (int k = 0; k < 8; ++k)
      a += hsh[n][q * 8 + k] * p0[(q * 8 + k) * 16 + j];
    a += __shfl_xor(a, 16);
    a += __shfl_xor(a, 32);           // all lanes: full sum for their j
    a = fmaxf(a + p1[j], 0.f);
    float q0 = a * p2[j * 2];
    float q1 = a * p2[j * 2 + 1];
    #pragma unroll
    for (int ofs = 1; ofs < 16; ofs <<= 1) {
      q0 += __shfl_xor(q0, ofs);
      q1 += __shfl_xor(q1, ofs);
    }
    if (lane == 0) {
      float* out = (float*)out0;
      const float vm = 1.f / (1.f + __expf(-(q0 + p3[0]))) + 0.5f;
      const float va = tanhf(q1 + p3[1]) * 180.f;
      out[(size_t)node * 2]     = vm;
      out[(size_t)node * 2 + 1] = va;
    }
  }
}

// ---------------- launch ----------------

extern "C" void kernel_launch(void* const* d_in, const int* in_sizes, int n_in,
                              void* d_out, int out_size, void* d_ws, size_t ws_size,
                              hipStream_t stream) {
  const float* x   = (const float*)d_in[0];
  const int*   ei  = (const int*)d_in[1];
  const float* w1l = (const float*)d_in[2];
  const float* b1l = (const float*)d_in[3];
  const float* w1r = (const float*)d_in[4];
  const float* b1r = (const float*)d_in[5];
  const float* a1  = (const float*)d_in[6];
  const float* c1  = (const float*)d_in[7];
  const float* w2l = (const float*)d_in[8];
  const float* b2l = (const float*)d_in[9];
  const float* w2r = (const float*)d_in[10];
  const float* b2r = (const float*)d_in[11];
  const float* a2  = (const float*)d_in[12];
  const float* c2  = (const float*)d_in[13];
  const float* w3l = (const float*)d_in[14];
  const float* b3l = (const float*)d_in[15];
  const float* w3r = (const float*)d_in[16];
  const float* b3r = (const float*)d_in[17];
  const float* a3  = (const float*)d_in[18];
  const float* c3  = (const float*)d_in[19];
  const float* wm1 = (const float*)d_in[20];
  const float* bm1 = (const float*)d_in[21];
  const float* wm2 = (const float*)d_in[22];
  const float* bm2 = (const float*)d_in[23];
  float* outp = (float*)d_out;
  (void)in_sizes; (void)n_in; (void)out_size; (void)ws_size;

  char* ws = (char*)d_ws;
  size_t o = 0;
  auto take = [&](size_t bytes) {
    char* p = ws + o;
    o = (o + bytes + 255) & ~(size_t)255;
    return p;
  };
  int* deg       = (int*)take((size_t)N * sizeof(int));
  int* ebuf      = (int*)take((size_t)N * S * sizeof(int));
  int* bcnt      = (int*)take((size_t)NBUK * 8 * sizeof(int));
  unsigned* bbuf = (unsigned*)take((size_t)NBUK * 8 * BCAP * sizeof(unsigned));
  __half* A      = (__half*)take((size_t)N * 128 * sizeof(__half));  // xl (fp16)
  __half* B      = (__half*)take((size_t)N * 128 * sizeof(__half));  // xr (fp16)
  __half* Cb     = (__half*)take((size_t)N * 128 * sizeof(__half));  // h / A3+B3
  __half* t1l    = (__half*)take(128 * 64 * sizeof(__half));   // WT fp16 swizzled
  __half* t1r    = (__half*)take(128 * 64 * sizeof(__half));
  __half* t2l    = (__half*)take(64 * 128 * sizeof(__half));
  __half* t2r    = (__half*)take(64 * 128 * sizeof(__half));
  __half* t3l    = (__half*)take(32 * 64 * sizeof(__half));
  __half* t3r    = (__half*)take(32 * 64 * sizeof(__half));
  __half* A3     = Cb;                 // layer-3 xl table (N x 32)
  __half* B3     = Cb + (size_t)N * 32;  // layer-3 xr table (N x 32)

  // --- weight prep (also zeroes bcnt) ---
  k_wprep<<<144, 256, 0, stream>>>(w1l, w1r, w2l, w2r, w3l, w3r,
                                   t1l, t1r, t2l, t2r, t3l, t3r, bcnt);

  // --- fused front: layer-1 L/R transform overlapped with edge binning ---
  k_front<<<XMM_B + BIN_B, 512, 0, stream>>>(x, t1l, t1r, b1l, b1r, A, B,
                                             ei, bcnt, bbuf);
  k_insert<<<NBUK, 256, 0, stream>>>(bcnt, bbuf, deg, ebuf);

  // --- layer 1 aggregation -> Cb (h, 128ch fp16) ---
  k_gat<4, 0><<<N / 4, 256, 0, stream>>>(A, B, a1, c1, deg, ebuf, Cb, nullptr,
                                         nullptr, nullptr,
                                         nullptr, nullptr, nullptr, nullptr);

  // --- layer 2 transform: 128 -> (2 heads x 32) x {L,R} ---
  k_xmm<128, 64, true><<<XMM_B, 512, 0, stream>>>(Cb, t2l, t2r, b2l, b2r, A, B);

  // --- layer 2 aggregation + fused layer-3 transform -> A3,B3 ---
  k_gat<2, 1><<<N / 4, 256, 0, stream>>>(A, B, a2, c2, deg, ebuf, A3, B3,
                                         t3l, t3r,
                                         b3l, b3r, nullptr, nullptr);

  // --- layer 3 aggregation + fused MLP head -> out ---
  k_gat<1, 2><<<N / 4, 256, 0, stream>>>(A3, B3, a3, c3, deg, ebuf, outp,
                                         nullptr, nullptr, nullptr,
                                         wm1, bm1, wm2, bm2);
}

// Round 15
// 366.366 us; speedup vs baseline: 1.1812x; 1.1812x over previous
//
#include <hip/hip_runtime.h>
#include <hip/hip_fp16.h>

// GATv2 x3 + MLP head on MI355X.
// R18 = R16 structure + W-halved xmm + bcnt-fold, MINUS R17's MODE-1 fusion.
// R17 lesson: a __syncthreads epilogue after the variable-length gather loop
// (deg=Poisson(17)) parks early waves at the barrier -> MLP collapse; gat<2,1>
// ran at 0.7 TB/s (137us). Layer-3 transform restored as standalone k_xmm.
// gat<1> keeps the fused MLP head (EPI=16 -> ~zero phase variance, barrier
// cheap, R16-verified). W-halving kept: front 3->5 blocks/CU, xmm2 2->3.

constexpr int N = 100000;
constexpr int E = 1600000;
constexpr int S = 48;       // slots per node (cap; stores guarded)

constexpr int NBUK = (N + 127) >> 7;          // 782 buckets of 128 nodes
constexpr int BCAP = 384;                     // per (bucket, class) cap; mean 256
constexpr int EPB = 8192;                     // edges per bin block
constexpr int BIN_B = (E + EPB - 1) / EPB;    // 196 bin blocks
constexpr int XMM_B = (N + 127) / 128;        // xmm blocks (128 nodes each)

typedef _Float16 half8_t __attribute__((ext_vector_type(8)));
typedef _Float16 half4_t __attribute__((ext_vector_type(4)));
typedef _Float16 h2 __attribute__((ext_vector_type(2)));
typedef float f32x4 __attribute__((ext_vector_type(4)));

// ---------------- bin body: block-local counting sort into (bucket,class) ---

template <int NT>
__device__ __forceinline__ void bin_body(const int* __restrict__ ei,
                                         int* __restrict__ bcnt,
                                         unsigned* __restrict__ bbuf,
                                         int blk, int cls) {
  __shared__ int hist[NBUK];
  const int tid = threadIdx.x;
  const int e0 = blk * EPB;
  for (int i = tid; i < NBUK; i += NT) hist[i] = 0;
  __syncthreads();
  // phase 1: LDS histogram of dst buckets (block-private)
  #pragma unroll 4
  for (int j = 0; j < EPB / NT; ++j) {
    const int e = e0 + j * NT + tid;
    if (e < E) atomicAdd(&hist[ei[E + e] >> 7], 1);
  }
  __syncthreads();
  // phase 2: reserve a contiguous range per bucket (one global atomic each)
  for (int i = tid; i < NBUK; i += NT) {
    const int h = hist[i];
    hist[i] = h ? atomicAdd(&bcnt[i * 8 + cls], h) : 0;
  }
  __syncthreads();
  // phase 3: scatter at base+rank (edge window is L2-hot from phase 1)
  #pragma unroll 4
  for (int j = 0; j < EPB / NT; ++j) {
    const int e = e0 + j * NT + tid;
    if (e < E) {
      const int src = ei[e];
      const int dst = ei[E + e];
      const int b = dst >> 7;
      const int pos = atomicAdd(&hist[b], 1);   // LDS: base + local rank
      if (pos < BCAP)
        bbuf[(size_t)(b * 8 + cls) * BCAP + pos] =
            ((unsigned)(dst & 127) << 17) | (unsigned)src;
    }
  }
}

// ---------------- pass 2: per-bucket insert with LDS slot claims ------------
// Slot 0 of every node is the (deterministic) self-loop.

__global__ __launch_bounds__(256) void k_insert(const int* __restrict__ bcnt,
                                                const unsigned* __restrict__ bbuf,
                                                int* __restrict__ deg,
                                                int* __restrict__ ebuf) {
  __shared__ int cnt[128];
  const int b = blockIdx.x;
  const int tid = threadIdx.x;
  const int node0 = b * 128 + tid;
  if (tid < 128) {
    cnt[tid] = 1;                                   // self-loop occupies slot 0
    if (node0 < N) ebuf[node0 * S] = node0;
  }
  __syncthreads();
  #pragma unroll 1
  for (int c = 0; c < 8; ++c) {
    const int n = min(bcnt[b * 8 + c], BCAP);
    const unsigned* arr = bbuf + (size_t)(b * 8 + c) * BCAP;
    for (int i = tid; i < n; i += 256) {
      const unsigned ent = arr[i];
      const int dlo = (int)(ent >> 17);
      const int src = (int)(ent & 0x1FFFFu);
      const int pos = atomicAdd(&cnt[dlo], 1);   // LDS atomic, block-exclusive
      if (pos < S) ebuf[(b * 128 + dlo) * S + pos] = src;
    }
  }
  __syncthreads();
  if (tid < 128 && node0 < N) deg[node0] = cnt[tid];
}

// ---------------- weight prep: fp32 [K][M] -> fp16 transposed+swizzled ------
// WT[m][k] stored at m*K + (k ^ ((m&7)<<3)). Also zeroes bcnt (fused memset).

template <int K, int M>
__device__ __forceinline__ void wprep_body(const float* __restrict__ src,
                                           __half* __restrict__ dst, int blk) {
  const int idx = blk * 256 + threadIdx.x;     // grid sized so idx < K*M
  const int k = idx / M;
  const int m = idx % M;
  ((_Float16*)dst)[m * K + (k ^ ((m & 7) << 3))] = (_Float16)src[idx];
}

__global__ __launch_bounds__(256) void k_wprep(
    const float* w1l, const float* w1r, const float* w2l, const float* w2r,
    const float* w3l, const float* w3r,
    __half* o1l, __half* o1r, __half* o2l, __half* o2r,
    __half* o3l, __half* o3r, int* bcnt) {
  const int gi = blockIdx.x * 256 + threadIdx.x;
  if (gi < NBUK * 8) bcnt[gi] = 0;
  int b = blockIdx.x;                 // sizes: 4x32 blocks (8192) + 2x8 (2048)
  if      (b < 32)  wprep_body<64, 128>(w1l, o1l, b);
  else if (b < 64)  wprep_body<64, 128>(w1r, o1r, b - 32);
  else if (b < 96)  wprep_body<128, 64>(w2l, o2l, b - 64);
  else if (b < 128) wprep_body<128, 64>(w2r, o2r, b - 96);
  else if (b < 136) wprep_body<64, 32>(w3l, o3l, b - 128);
  else              wprep_body<64, 32>(w3r, o3r, b - 136);
}

// ---------------- MFMA transform body: y = x @ w + b, L and R fused ---------
// Block: 128 nodes, 8 waves, 512 threads; wave = 16 rows x M cols.
// W-halved LDS: stage WT_l -> MFMA L -> restage WT_r -> MFMA R.

template <int K, int M, bool FP16IN>
__device__ __forceinline__ void xmm_body(const void* __restrict__ xin,
                                         const __half* __restrict__ wtl,
                                         const __half* __restrict__ wtr,
                                         const float* __restrict__ bl,
                                         const float* __restrict__ br,
                                         __half* __restrict__ Aout,
                                         __half* __restrict__ Bout, int blk) {
  constexpr int NPB = 128;           // nodes per block
  constexpr int XSZ = NPB * K;       // halfs
  constexpr int WSZ = M * K;         // halfs per weight matrix
  constexpr int KS = K / 32;         // MFMA k-steps
  constexpr int CT = M / 16;         // col tiles
  constexpr int PSZ = (XSZ + WSZ) > (NPB * M) ? (XSZ + WSZ) : (NPB * M);
  __shared__ _Float16 pool[PSZ];

  const int tid = threadIdx.x;
  const int node0 = blk * NPB;

  // --- stage X tile (swizzled) ---
  if constexpr (!FP16IN) {
    const float* x = (const float*)xin;
    for (int i = tid; i < NPB * (K / 4); i += 512) {
      const int row = i / (K / 4);
      const int c4 = i % (K / 4);
      const int grow = min(node0 + row, N - 1);
      float4 v = reinterpret_cast<const float4*>(x)[(size_t)grow * (K / 4) + c4];
      const int k0 = c4 * 4;
      const int hidx = row * K + (k0 ^ ((row & 7) << 3));
      *reinterpret_cast<half4_t*>(&pool[hidx]) =
          (half4_t){(_Float16)v.x, (_Float16)v.y, (_Float16)v.z, (_Float16)v.w};
    }
  } else {
    const uint4* x = (const uint4*)xin;   // rows of K halfs
    for (int i = tid; i < NPB * (K / 8); i += 512) {
      const int row = i / (K / 8);
      const int c8 = i % (K / 8);
      const int grow = min(node0 + row, N - 1);
      uint4 v = x[(size_t)grow * (K / 8) + c8];
      const int k0 = c8 * 8;
      *reinterpret_cast<uint4*>(&pool[row * K + (k0 ^ ((row & 7) << 3))]) = v;
    }
  }
  // --- stage WT_l ---
  for (int i = tid; i < WSZ / 8; i += 512)
    reinterpret_cast<uint4*>(&pool[XSZ])[i] =
        reinterpret_cast<const uint4*>(wtl)[i];
  __syncthreads();

  const int lane = tid & 63;
  const int wid = tid >> 6;          // 0..7
  const int r0 = wid * 16;

  // --- A fragments (persist across both W phases) ---
  half8_t af[KS];
  #pragma unroll
  for (int ks = 0; ks < KS; ++ks) {
    const int row = r0 + (lane & 15);
    const int k0 = ks * 32 + (lane >> 4) * 8;
    af[ks] = *reinterpret_cast<const half8_t*>(
        &pool[row * K + (k0 ^ ((row & 7) << 3))]);
  }

  f32x4 accl[CT], accr[CT];
  #pragma unroll
  for (int ct = 0; ct < CT; ++ct) {
    accl[ct] = (f32x4){0.f, 0.f, 0.f, 0.f};
    accr[ct] = (f32x4){0.f, 0.f, 0.f, 0.f};
  }

  #pragma unroll
  for (int ct = 0; ct < CT; ++ct) {
    #pragma unroll
    for (int ks = 0; ks < KS; ++ks) {
      const int col = ct * 16 + (lane & 15);
      const int k0 = ks * 32 + (lane >> 4) * 8;
      half8_t bf = *reinterpret_cast<const half8_t*>(
          &pool[XSZ + col * K + (k0 ^ ((col & 7) << 3))]);
      accl[ct] = __builtin_amdgcn_mfma_f32_16x16x32_f16(af[ks], bf, accl[ct], 0, 0, 0);
    }
  }
  __syncthreads();
  // --- restage WT_r into the same region ---
  for (int i = tid; i < WSZ / 8; i += 512)
    reinterpret_cast<uint4*>(&pool[XSZ])[i] =
        reinterpret_cast<const uint4*>(wtr)[i];
  __syncthreads();
  #pragma unroll
  for (int ct = 0; ct < CT; ++ct) {
    #pragma unroll
    for (int ks = 0; ks < KS; ++ks) {
      const int col = ct * 16 + (lane & 15);
      const int k0 = ks * 32 + (lane >> 4) * 8;
      half8_t bf = *reinterpret_cast<const half8_t*>(
          &pool[XSZ + col * K + (k0 ^ ((col & 7) << 3))]);
      accr[ct] = __builtin_amdgcn_mfma_f32_16x16x32_f16(af[ks], bf, accr[ct], 0, 0, 0);
    }
  }

  // --- epilogue: D -> LDS (unswizzled) -> coalesced global stores ---
  __syncthreads();   // staging regions dead; D region aliases pool[0..NPB*M)
  #pragma unroll
  for (int ct = 0; ct < CT; ++ct) {
    const int col = ct * 16 + (lane & 15);
    const float bb = bl[col];
    #pragma unroll
    for (int r = 0; r < 4; ++r) {
      const int row = r0 + (lane >> 4) * 4 + r;
      pool[row * M + col] = (_Float16)(accl[ct][r] + bb);
    }
  }
  __syncthreads();
  for (int i = tid; i < NPB * (M / 8); i += 512) {
    const int row = i / (M / 8);
    const int j = i % (M / 8);
    const int g = node0 + row;
    if (g < N)
      reinterpret_cast<uint4*>(Aout + (size_t)g * M)[j] =
          reinterpret_cast<uint4*>(&pool[row * M])[j];
  }
  __syncthreads();
  #pragma unroll
  for (int ct = 0; ct < CT; ++ct) {
    const int col = ct * 16 + (lane & 15);
    const float bb = br[col];
    #pragma unroll
    for (int r = 0; r < 4; ++r) {
      const int row = r0 + (lane >> 4) * 4 + r;
      pool[row * M + col] = (_Float16)(accr[ct][r] + bb);
    }
  }
  __syncthreads();
  for (int i = tid; i < NPB * (M / 8); i += 512) {
    const int row = i / (M / 8);
    const int j = i % (M / 8);
    const int g = node0 + row;
    if (g < N)
      reinterpret_cast<uint4*>(Bout + (size_t)g * M)[j] =
          reinterpret_cast<uint4*>(&pool[row * M])[j];
  }
}

// ---------------- fused front: layer-1 xmm blocks + bin blocks -------------

__global__ __launch_bounds__(512) void k_front(const float* __restrict__ x,
                                               const __half* __restrict__ t1l,
                                               const __half* __restrict__ t1r,
                                               const float* __restrict__ b1l,
                                               const float* __restrict__ b1r,
                                               __half* __restrict__ A,
                                               __half* __restrict__ B,
                                               const int* __restrict__ ei,
                                               int* __restrict__ bcnt,
                                               unsigned* __restrict__ bbuf) {
  const int blk = blockIdx.x;
  if (blk < XMM_B) {
    xmm_body<64, 128, false>(x, t1l, t1r, b1l, b1r, A, B, blk);
    return;
  }
  bin_body<512>(ei, bcnt, bbuf, blk - XMM_B, blk & 7);
}

// ---------------- standalone xmm (layers 2, 3) ----------------

template <int K, int M, bool FP16IN>
__global__ __launch_bounds__(512) void k_xmm(const void* __restrict__ xin,
                                             const __half* __restrict__ wtl,
                                             const __half* __restrict__ wtr,
                                             const float* __restrict__ bl,
                                             const float* __restrict__ br,
                                             __half* __restrict__ Aout,
                                             __half* __restrict__ Bout) {
  xmm_body<K, M, FP16IN>(xin, wtl, wtr, bl, br, Aout, Bout, blockIdx.x);
}

// ---------------- GATv2 aggregation: one wave per dst node ----------------
// Lane holds 8 fp16 features; one wave load covers a full row. Packed fp16
// score path + v_dot2_f32_f16; fp32 acc via v_fma_mix. 2-phase A/B pipeline
// (R13 known-good). MODE: 0=plain fp16 out, 2=fused MLP head (gat<1> only;
// EPI=16 -> near-zero loop-length variance so the barrier is cheap).

template <int CTRL>
__device__ __forceinline__ float dpp_add(float x) {
  return x + __builtin_bit_cast(float,
      __builtin_amdgcn_update_dpp(0, __builtin_bit_cast(int, x),
                                  CTRL, 0xF, 0xF, true));
}

template <int H, int MODE>
__global__ __launch_bounds__(256) void k_gat(const __half* __restrict__ xl,
                                             const __half* __restrict__ xr,
                                             const float* __restrict__ att,
                                             const float* __restrict__ bias,
                                             const int* __restrict__ deg,
                                             const int* __restrict__ ebuf,
                                             void* __restrict__ outv,
                                             const float* __restrict__ wm1,
                                             const float* __restrict__ bm1,
                                             const float* __restrict__ wm2,
                                             const float* __restrict__ bm2) {
  constexpr int F = H * 32;
  constexpr int F8 = F / 8;        // 16B chunks (8 halfs) per row
  constexpr int LPE = F8;          // lanes per edge: 16 / 8 / 4
  constexpr int EPI = 64 / LPE;    // edges per iteration: 4 / 8 / 16
  constexpr float LOG2E = 1.44269504088896f;
  const int lane = threadIdx.x & 63;
  const int node = (blockIdx.x * blockDim.x + threadIdx.x) >> 6;
  if (node >= N) return;    // never taken (N % 4 == 0, exact grid)
  const int li = lane & (LPE - 1);  // 16B chunk index within row
  const int eg = lane / LPE;

  const uint4* xl4 = reinterpret_cast<const uint4*>(xl);
  const uint4* xr4 = reinterpret_cast<const uint4*>(xr);

  // xi: 8 fp16 channels kept packed
  const uint4 xiraw = xr4[(unsigned)node * F8 + li];
  h2 xi2[4];
  xi2[0] = __builtin_bit_cast(h2, xiraw.x);
  xi2[1] = __builtin_bit_cast(h2, xiraw.y);
  xi2[2] = __builtin_bit_cast(h2, xiraw.z);
  xi2[3] = __builtin_bit_cast(h2, xiraw.w);

  // att: fp32 -> pre-scaled fp16 pairs
  const float4 at0 = reinterpret_cast<const float4*>(att)[li * 2];
  const float4 at1 = reinterpret_cast<const float4*>(att)[li * 2 + 1];
  h2 at2[4];
  at2[0] = (h2){(_Float16)(at0.x * LOG2E), (_Float16)(at0.y * LOG2E)};
  at2[1] = (h2){(_Float16)(at0.z * LOG2E), (_Float16)(at0.w * LOG2E)};
  at2[2] = (h2){(_Float16)(at1.x * LOG2E), (_Float16)(at1.y * LOG2E)};
  at2[3] = (h2){(_Float16)(at1.z * LOG2E), (_Float16)(at1.w * LOG2E)};
  const h2 c02 = {(_Float16)0.2f, (_Float16)0.2f};

  float4 acc0 = make_float4(0.f, 0.f, 0.f, 0.f);
  float4 acc1 = make_float4(0.f, 0.f, 0.f, 0.f);
  float l = 0.f;

  const int* row = ebuf + node * S;
  const int dn = min(deg[node], S);   // deg >= 1 (self loop)
  const int last = dn - 1;
  const int iters = (dn + EPI - 1) / EPI;

  auto process = [&](const uint4& raw, bool valid) {
    h2 xj0 = __builtin_bit_cast(h2, raw.x);
    h2 xj1 = __builtin_bit_cast(h2, raw.y);
    h2 xj2 = __builtin_bit_cast(h2, raw.z);
    h2 xj3 = __builtin_bit_cast(h2, raw.w);
    float t = 0.f;
    h2 v;
    v = xi2[0] + xj0; v = __builtin_elementwise_max(v, v * c02);
    t = __builtin_amdgcn_fdot2(at2[0], v, t, false);
    v = xi2[1] + xj1; v = __builtin_elementwise_max(v, v * c02);
    t = __builtin_amdgcn_fdot2(at2[1], v, t, false);
    v = xi2[2] + xj2; v = __builtin_elementwise_max(v, v * c02);
    t = __builtin_amdgcn_fdot2(at2[2], v, t, false);
    v = xi2[3] + xj3; v = __builtin_elementwise_max(v, v * c02);
    t = __builtin_amdgcn_fdot2(at2[3], v, t, false);
    // head = one 4-lane quad: butterfly via quad_perm DPP (VALU, no LDS pipe)
    t = dpp_add<0xB1>(t);   // xor 1: [1,0,3,2]
    t = dpp_add<0x4E>(t);   // xor 2: [2,3,0,1]
    float pm = valid ? exp2f(t) : 0.f;
    l += pm;
    // fp32 acc; (float)h * f + acc folds to v_fma_mix_f32
    acc0.x = fmaf(pm, (float)xj0[0], acc0.x);
    acc0.y = fmaf(pm, (float)xj0[1], acc0.y);
    acc0.z = fmaf(pm, (float)xj1[0], acc0.z);
    acc0.w = fmaf(pm, (float)xj1[1], acc0.w);
    acc1.x = fmaf(pm, (float)xj2[0], acc1.x);
    acc1.y = fmaf(pm, (float)xj2[1], acc1.y);
    acc1.z = fmaf(pm, (float)xj3[0], acc1.z);
    acc1.w = fmaf(pm, (float)xj3[1], acc1.w);
  };

  // pipeline warm-up: src prefetched 2 iterations ahead, gather 1 ahead
  int i = eg;
  bool vA = i < dn;
  int s0 = row[min(i, last)];
  i += EPI;
  uint4 xjA = xl4[(unsigned)s0 * F8 + li];
  bool vB = i < dn;
  int sN = row[min(i, last)];
  i += EPI;
  uint4 xjB;

  for (int it = 0; it < iters; it += 2) {
    // ---- phase A ----
    xjB = xl4[(unsigned)sN * F8 + li];             // gather it+1
    bool vn = i < dn;
    sN = row[min(i, last)];                        // src it+2
    i += EPI;
    process(xjA, vA);
    vA = vn;
    // ---- phase B ----
    xjA = xl4[(unsigned)sN * F8 + li];             // gather it+2
    vn = i < dn;
    sN = row[min(i, last)];                        // src it+3
    i += EPI;
    process(xjB, vB);
    vB = vn;
  }

  // combine the EPI edge slots (once per node)
  #pragma unroll
  for (int ofs = LPE; ofs < 64; ofs <<= 1) {
    acc0.x += __shfl_xor(acc0.x, ofs);
    acc0.y += __shfl_xor(acc0.y, ofs);
    acc0.z += __shfl_xor(acc0.z, ofs);
    acc0.w += __shfl_xor(acc0.w, ofs);
    acc1.x += __shfl_xor(acc1.x, ofs);
    acc1.y += __shfl_xor(acc1.y, ofs);
    acc1.z += __shfl_xor(acc1.z, ofs);
    acc1.w += __shfl_xor(acc1.w, ofs);
    l      += __shfl_xor(l, ofs);
  }

  if constexpr (MODE == 0) {
    __half* out = (__half*)outv;
    if (lane < LPE) {
      const float inv = 1.f / (l + 1e-16f);
      const float4 bv0 = reinterpret_cast<const float4*>(bias)[li * 2];
      const float4 bv1 = reinterpret_cast<const float4*>(bias)[li * 2 + 1];
      float r[8];
      r[0] = fmaxf(acc0.x * inv + bv0.x, 0.f);
      r[1] = fmaxf(acc0.y * inv + bv0.y, 0.f);
      r[2] = fmaxf(acc0.z * inv + bv0.z, 0.f);
      r[3] = fmaxf(acc0.w * inv + bv0.w, 0.f);
      r[4] = fmaxf(acc1.x * inv + bv1.x, 0.f);
      r[5] = fmaxf(acc1.y * inv + bv1.y, 0.f);
      r[6] = fmaxf(acc1.z * inv + bv1.z, 0.f);
      r[7] = fmaxf(acc1.w * inv + bv1.w, 0.f);
      uint4 o;
      #pragma unroll
      for (int p = 0; p < 4; ++p) {
        const h2 hh = {(_Float16)r[2 * p], (_Float16)r[2 * p + 1]};
        (&o.x)[p] = __builtin_bit_cast(unsigned, hh);
      }
      reinterpret_cast<uint4*>(out)[(unsigned)node * F8 + li] = o;
    }
  } else {
    // ---- fused MLP head: h row -> LDS -> 32->16->2 + sigmoid/tanh ----
    __shared__ float hsh[4][32];
    if (lane < LPE) {
      const float inv = 1.f / (l + 1e-16f);
      const float4 bv0 = reinterpret_cast<const float4*>(bias)[li * 2];
      const float4 bv1 = reinterpret_cast<const float4*>(bias)[li * 2 + 1];
      float* hr = &hsh[threadIdx.x >> 6][li * 8];
      hr[0] = fmaxf(acc0.x * inv + bv0.x, 0.f);
      hr[1] = fmaxf(acc0.y * inv + bv0.y, 0.f);
      hr[2] = fmaxf(acc0.z * inv + bv0.z, 0.f);
      hr[3] = fmaxf(acc0.w * inv + bv0.w, 0.f);
      hr[4] = fmaxf(acc1.x * inv + bv1.x, 0.f);
      hr[5] = fmaxf(acc1.y * inv + bv1.y, 0.f);
      hr[6] = fmaxf(acc1.z * inv + bv1.z, 0.f);
      hr[7] = fmaxf(acc1.w * inv + bv1.w, 0.f);
    }
    __syncthreads();
    const int n = threadIdx.x >> 6;   // node slot within block
    const int j = lane & 15;          // hidden unit
    const int q = lane >> 4;          // k-octet
    float a = 0.f;
    #pragma unroll
    for (int k = 0; k < 8; ++k)
      a += hsh[n][q * 8 + k] * wm1[(q * 8 + k) * 16 + j];
    a += __shfl_xor(a, 16);
    a += __shfl_xor(a, 32);           // all lanes: full sum for their j
    a = fmaxf(a + bm1[j], 0.f);
    float q0 = a * wm2[j * 2];
    float q1 = a * wm2[j * 2 + 1];
    #pragma unroll
    for (int ofs = 1; ofs < 16; ofs <<= 1) {
      q0 += __shfl_xor(q0, ofs);
      q1 += __shfl_xor(q1, ofs);
    }
    if (lane == 0) {
      float* out = (float*)outv;
      const float vm = 1.f / (1.f + __expf(-(q0 + bm2[0]))) + 0.5f;
      const float va = tanhf(q1 + bm2[1]) * 180.f;
      out[(size_t)node * 2]     = vm;
      out[(size_t)node * 2 + 1] = va;
    }
  }
}

// ---------------- launch ----------------

extern "C" void kernel_launch(void* const* d_in, const int* in_sizes, int n_in,
                              void* d_out, int out_size, void* d_ws, size_t ws_size,
                              hipStream_t stream) {
  const float* x   = (const float*)d_in[0];
  const int*   ei  = (const int*)d_in[1];
  const float* w1l = (const float*)d_in[2];
  const float* b1l = (const float*)d_in[3];
  const float* w1r = (const float*)d_in[4];
  const float* b1r = (const float*)d_in[5];
  const float* a1  = (const float*)d_in[6];
  const float* c1  = (const float*)d_in[7];
  const float* w2l = (const float*)d_in[8];
  const float* b2l = (const float*)d_in[9];
  const float* w2r = (const float*)d_in[10];
  const float* b2r = (const float*)d_in[11];
  const float* a2  = (const float*)d_in[12];
  const float* c2  = (const float*)d_in[13];
  const float* w3l = (const float*)d_in[14];
  const float* b3l = (const float*)d_in[15];
  const float* w3r = (const float*)d_in[16];
  const float* b3r = (const float*)d_in[17];
  const float* a3  = (const float*)d_in[18];
  const float* c3  = (const float*)d_in[19];
  const float* wm1 = (const float*)d_in[20];
  const float* bm1 = (const float*)d_in[21];
  const float* wm2 = (const float*)d_in[22];
  const float* bm2 = (const float*)d_in[23];
  float* outp = (float*)d_out;
  (void)in_sizes; (void)n_in; (void)out_size; (void)ws_size;

  char* ws = (char*)d_ws;
  size_t o = 0;
  auto take = [&](size_t bytes) {
    char* p = ws + o;
    o = (o + bytes + 255) & ~(size_t)255;
    return p;
  };
  int* deg       = (int*)take((size_t)N * sizeof(int));
  int* ebuf      = (int*)take((size_t)N * S * sizeof(int));
  int* bcnt      = (int*)take((size_t)NBUK * 8 * sizeof(int));
  unsigned* bbuf = (unsigned*)take((size_t)NBUK * 8 * BCAP * sizeof(unsigned));
  __half* A      = (__half*)take((size_t)N * 128 * sizeof(__half));  // xl (fp16)
  __half* B      = (__half*)take((size_t)N * 128 * sizeof(__half));  // xr (fp16)
  __half* Cb     = (__half*)take((size_t)N * 128 * sizeof(__half));  // h (fp16)
  __half* t1l    = (__half*)take(128 * 64 * sizeof(__half));   // WT fp16 swizzled
  __half* t1r    = (__half*)take(128 * 64 * sizeof(__half));
  __half* t2l    = (__half*)take(64 * 128 * sizeof(__half));
  __half* t2r    = (__half*)take(64 * 128 * sizeof(__half));
  __half* t3l    = (__half*)take(32 * 64 * sizeof(__half));
  __half* t3r    = (__half*)take(32 * 64 * sizeof(__half));

  // --- weight prep (also zeroes bcnt) ---
  k_wprep<<<144, 256, 0, stream>>>(w1l, w1r, w2l, w2r, w3l, w3r,
                                   t1l, t1r, t2l, t2r, t3l, t3r, bcnt);

  // --- fused front: layer-1 L/R transform overlapped with edge binning ---
  k_front<<<XMM_B + BIN_B, 512, 0, stream>>>(x, t1l, t1r, b1l, b1r, A, B,
                                             ei, bcnt, bbuf);
  k_insert<<<NBUK, 256, 0, stream>>>(bcnt, bbuf, deg, ebuf);

  // --- layer 1 aggregation -> Cb (h, 128ch fp16) ---
  k_gat<4, 0><<<N / 4, 256, 0, stream>>>(A, B, a1, c1, deg, ebuf, Cb,
                                         nullptr, nullptr, nullptr, nullptr);

  // --- layer 2: 128 -> (2 heads x 32), concat ---
  k_xmm<128, 64, true><<<XMM_B, 512, 0, stream>>>(Cb, t2l, t2r, b2l, b2r, A, B);
  k_gat<2, 0><<<N / 4, 256, 0, stream>>>(A, B, a2, c2, deg, ebuf, Cb,
                                         nullptr, nullptr, nullptr, nullptr);

  // --- layer 3: 64 -> (1 head x 32), mean == identity; MLP head fused ---
  k_xmm<64, 32, true><<<XMM_B, 512, 0, stream>>>(Cb, t3l, t3r, b3l, b3r, A, B);
  k_gat<1, 2><<<N / 4, 256, 0, stream>>>(A, B, a3, c3, deg, ebuf, outp,
                                         wm1, bm1, wm2, bm2);
}